// Round 8
// baseline (223.222 us; speedup 1.0000x reference)
//
#include <hip/hip_runtime.h>

#define B_ 8
#define CIN_ 256
#define COUT_ 256

typedef short short8_t __attribute__((ext_vector_type(8)));
typedef float float16_t __attribute__((ext_vector_type(16)));

// ws layout (shorts): dwA [0, DWA) ; xpre [DWA, DWA+XPRE)
#define DWA_SHORTS   (B_ * 2 * 8 * 9 * 4 * 128 * 8)   // 4,718,592
#define XPRE_SHORTS  (B_ * 8 * 66 * 4 * 66 * 8)       // 8,921,088

__device__ __forceinline__ unsigned short f2bf(float f) {
    union { float f; unsigned u; } v; v.f = f;
    unsigned u = v.u;
    unsigned r = (u + 0x7fffu + ((u >> 16) & 1u)) >> 16;  // RNE
    return (unsigned short)r;
}

// K1: one dispatch, two block roles.
// blocks [0,4224): pack x -> xpre bf16 [b][cb8][h66][g4][w66][ci8] (halos zeroed)
// blocks [4224,4288): per (b, co-group-of-32): compute 1/sigma in-block, pack
//                     weights -> dwA bf16 [b][co_blk2][cb8][tap9][g4][co128][ci8]
__global__ __launch_bounds__(256) void k_prep(const float* __restrict__ x,
                                              const float* __restrict__ style,
                                              const float* __restrict__ weight,
                                              unsigned short* __restrict__ xpre,
                                              unsigned short* __restrict__ dwA) {
    const int bid = blockIdx.x;
    const int t = threadIdx.x;

    if (bid < 4224) {  // ---- xpre pack (validated R6 path) ----
        const int h_out = bid % 66;
        const int t2 = bid / 66;
        const int cb = t2 & 7, b = t2 >> 3;
        const int h_in = h_out - 1;
        const int g = t >> 6, lane = t & 63;
        unsigned short* dst =
            xpre + (((size_t)(b * 8 + cb) * 66 + h_out) * 4 + g) * (66 * 8);
#pragma unroll
        for (int pass = 0; pass < 2; ++pass) {
            int w_out = pass * 64 + lane;
            if (pass == 1 && lane >= 2) break;
            int w_in = w_out - 1;
            short8_t v = (short8_t){0, 0, 0, 0, 0, 0, 0, 0};
            if ((unsigned)h_in < 64u && (unsigned)w_in < 64u) {
                const float* xp =
                    x + (((size_t)(b * CIN_ + cb * 32 + g * 8)) * 64 + h_in) * 64 + w_in;
#pragma unroll
                for (int j = 0; j < 8; ++j) v[j] = (short)f2bf(xp[(size_t)j * 4096]);
            }
            *(short8_t*)(dst + (size_t)w_out * 8) = v;
        }
    } else {  // ---- wpack with in-block inv ----
        __shared__ float sinv[32];
        const int j = bid - 4224;
        const int b = j >> 3, grp = j & 7;

        // inv: thread = co_l*8 + cpart; cpart covers ci = cpart*32..+31
        const int co_l = t >> 3, cpart = t & 7;
        const int co = grp * 32 + co_l;
        const float* wco = weight + (size_t)co * 2304;
        float acc = 0.f;
#pragma unroll 4
        for (int c2 = 0; c2 < 32; ++c2) {
            int ci = cpart * 32 + c2;
            float a = 0.f;
#pragma unroll
            for (int tp = 0; tp < 9; ++tp) { float w = wco[ci * 9 + tp]; a += w * w; }
            float s = style[b * CIN_ + ci];
            acc += s * s * a;
        }
        acc += __shfl_xor(acc, 1, 64);
        acc += __shfl_xor(acc, 2, 64);
        acc += __shfl_xor(acc, 4, 64);
        if (cpart == 0) sinv[co_l] = 1.0f / sqrtf(acc + 1e-8f);
        __syncthreads();

        // pack: 9216 octets; c -> [cb8][tap9][g4][co32]
        const int co_blk = grp >> 2;
#pragma unroll 4
        for (int i = 0; i < 36; ++i) {
            int c = t + i * 256;
            int cb = c / 1152;
            int r = c - cb * 1152;
            int tap = r >> 7;
            int r2 = r & 127;
            int g = r2 >> 5, co32 = r2 & 31;
            int coo = grp * 32 + co32;
            int co128 = (grp & 3) * 32 + co32;
            int ci0 = cb * 32 + g * 8;
            const float iv = sinv[co32];
            const float* wp = weight + (size_t)coo * 2304;
            short8_t v;
#pragma unroll
            for (int k = 0; k < 8; ++k)
                v[k] = (short)f2bf(wp[(ci0 + k) * 9 + tap] * style[b * CIN_ + ci0 + k] * iv);
            unsigned short* slab =
                dwA + (((size_t)(b * 2 + co_blk) * 8 + cb) * 9 + tap) * 4096;
            *(short8_t*)(slab + (size_t)(g * 128 + co128) * 8) = v;
        }
    }
}

// K2: conv as 9 shifted GEMMs. Block = 128co x 64col x 1 row, 4 waves =
// 2(co64) x 2(col32); wave tile M64xN32 (acc 32 VGPR) -> grid 1024, 16
// waves/CU (4/SIMD) for latency hiding. Double-buffered contiguous LDS slab.
__global__ __launch_bounds__(256, 4) void k_conv(const unsigned short* __restrict__ xpre,
                                                 const unsigned short* __restrict__ dwA,
                                                 float* __restrict__ out) {
    __shared__ __align__(16) unsigned short xs[2][3 * 4 * 66 * 8];  // 2 x 12.4 KB

    const int row = blockIdx.x;      // 0..63
    const int co_blk = blockIdx.y;   // 0..1
    const int b = blockIdx.z;        // 0..7
    const int tid = threadIdx.x;
    const int lane = tid & 63, wid = tid >> 6;
    const int wave_m = wid & 1;      // co64 half
    const int wave_n = wid >> 1;     // col32 half
    const int l32 = lane & 31, kh = lane >> 5;

    float16_t acc[2];
#pragma unroll
    for (int mi = 0; mi < 2; ++mi)
#pragma unroll
        for (int r = 0; r < 16; ++r) acc[mi][r] = 0.f;

    // staging: per cb one contiguous 6336-short slab (3 h-rows: row..row+2)
    short8_t st[4];
    auto load_regs = [&](int cb) {
        const unsigned short* s = xpre + ((size_t)(b * 8 + cb) * 66 + row) * 2112;
#pragma unroll
        for (int it = 0; it < 3; ++it)
            st[it] = *(const short8_t*)(s + (size_t)(tid + it * 256) * 8);
        if (tid < 24) st[3] = *(const short8_t*)(s + (size_t)(tid + 768) * 8);
    };
    auto store_lds = [&](int buf) {
        unsigned short* d = xs[buf];
#pragma unroll
        for (int it = 0; it < 3; ++it)
            *(short8_t*)(d + (size_t)(tid + it * 256) * 8) = st[it];
        if (tid < 24) *(short8_t*)(d + (size_t)(tid + 768) * 8) = st[3];
    };

    // A frags: depth-3 rotation, distance-2 prefetch (tap%3 is cb-consistent)
    short8_t abuf[3][4];
    auto loadA = [&](short8_t* dst, int acb, int atap) {
        const unsigned short* Ab =
            dwA + (((size_t)(b * 2 + co_blk) * 8 + acb) * 9 + atap) * 4096;
        const int co_off = wave_m * 64 + l32;
#pragma unroll
        for (int ks = 0; ks < 2; ++ks)
#pragma unroll
            for (int mi = 0; mi < 2; ++mi)
                dst[ks * 2 + mi] = *(const short8_t*)(
                    Ab + (size_t)((ks * 2 + kh) * 128 + co_off + mi * 32) * 8);
    };

    load_regs(0);
    loadA(abuf[0], 0, 0);
    loadA(abuf[1], 0, 1);

    for (int cb = 0; cb < 8; ++cb) {
        store_lds(cb & 1);
        __syncthreads();
        if (cb < 7) load_regs(cb + 1);

        const unsigned short* xb = xs[cb & 1];
#pragma unroll
        for (int tap = 0; tap < 9; ++tap) {
            const int nl = tap + 2;
            const int acb = cb + nl / 9, atap = nl % 9;
            if (acb < 8) loadA(abuf[(tap + 2) % 3], acb, atap);

            const int dh = tap / 3, dwc = tap - dh * 3;
            // LDS [hrow3][g4][w66][8]; col = wave_n*32 + l32 + dwc; g = ks*2+kh
            const unsigned short* bb =
                xb + (size_t)((dh * 4 + kh) * 66 + wave_n * 32 + l32 + dwc) * 8;
            short8_t bf[2];
#pragma unroll
            for (int ks = 0; ks < 2; ++ks)
                bf[ks] = *(const short8_t*)(bb + (size_t)(ks * 2 * 66) * 8);

            const short8_t* ac = abuf[tap % 3];
#pragma unroll
            for (int ks = 0; ks < 2; ++ks)
#pragma unroll
                for (int mi = 0; mi < 2; ++mi)
                    acc[mi] = __builtin_amdgcn_mfma_f32_32x32x16_bf16(
                        ac[ks * 2 + mi], bf[ks], acc[mi], 0, 0, 0);
        }
    }

    // epilogue: 32x32 C/D: col = lane&31, co_off = (r&3) + 8*(r>>2) + 4*kh
    const int col = wave_n * 32 + l32;
#pragma unroll
    for (int mi = 0; mi < 2; ++mi)
#pragma unroll
        for (int r = 0; r < 16; ++r) {
            int co = co_blk * 128 + wave_m * 64 + mi * 32 + (r & 3) + 8 * (r >> 2) + 4 * kh;
            out[(((size_t)b * COUT_ + co) * 64 + row) * 64 + col] = acc[mi][r];
        }
}

extern "C" void kernel_launch(void* const* d_in, const int* in_sizes, int n_in,
                              void* d_out, int out_size, void* d_ws, size_t ws_size,
                              hipStream_t stream) {
    const float* x = (const float*)d_in[0];
    const float* style = (const float*)d_in[1];
    const float* weight = (const float*)d_in[2];
    float* out = (float*)d_out;

    unsigned short* dwA = (unsigned short*)d_ws;
    unsigned short* xpre = dwA + DWA_SHORTS;

    k_prep<<<dim3(4288), 256, 0, stream>>>(x, style, weight, xpre, dwA);
    k_conv<<<dim3(64, 2, B_), 256, 0, stream>>>(xpre, dwA, out);
}